// Round 6
// baseline (182.945 us; speedup 1.0000x reference)
//
#include <hip/hip_runtime.h>
#include <math.h>

#define NV 4096      // variable nodes
#define MC 2048      // check nodes
#define DV 3
#define DC 6
#define NE (NV * DV) // 12288 edges
#define NB 2048      // batch
#define NITER 5
#define TPB 1024     // 16 waves/block; 2 blocks/CU -> 32 waves/CU
#define CNW 8        // words per CN row (6 used + 2 pad), 32B stride
#define LDSW (MC * CNW)  // 16384 words = 64KB

// LDS layout: CN c's 6 messages live in two 16B chunks.
// chunk(c,k) = 2c + (k ^ ((c>>2)&1)) -- XOR swizzle: within any 8 lanes the
// b128/b64 reads tile all 32 banks exactly once (verified by hand, lanes 0-7).
__host__ __device__ __forceinline__ int chunk_of(int c, int k) {
    return 2 * c + (k ^ ((c >> 2) & 1));
}
__host__ __device__ __forceinline__ int word_of(int c, int j) {
    return chunk_of(c, j >> 2) * 4 + (j & 3);
}

// Build per-check-node edge lists (slot order arbitrary due to atomics).
__global__ __launch_bounds__(256) void build_cn(const int* __restrict__ cn_idx,
                                                int* __restrict__ cn_edges,
                                                int* __restrict__ cn_cnt) {
    int e = blockIdx.x * 256 + threadIdx.x;
    if (e < NE) {
        int m = cn_idx[e];
        int slot = atomicAdd(&cn_cnt[m], 1);
        cn_edges[m * DC + slot] = e;
    }
}

// Sort each CN's 6 edges ascending (deterministic, matches ref edge order)
// and emit the edge -> swizzled-LDS-word map for the VN side.
__global__ __launch_bounds__(256) void sort_cn(int* __restrict__ cn_edges,
                                               int* __restrict__ vn_word) {
    int m = blockIdx.x * 256 + threadIdx.x;
    if (m < MC) {
        int v[DC];
        for (int j = 0; j < DC; ++j) v[j] = cn_edges[m * DC + j];
        for (int i = 1; i < DC; ++i) {
            int key = v[i]; int j = i - 1;
            while (j >= 0 && v[j] > key) { v[j + 1] = v[j]; --j; }
            v[j + 1] = key;
        }
        for (int j = 0; j < DC; ++j) {
            cn_edges[m * DC + j] = v[j];
            vn_word[v[j]] = word_of(m, j);
        }
    }
}

// One workgroup per batch element; messages in LDS, CN-major swizzled rows.
// CN update in product domain: u = e^{-|mw|}; Pp/Pm = exclusion products of
// (1+u)/(1-u); 2*atanh(Pm/Pp) = ln((Pp+Pm)/(Pp-Pm)).
// Reference clips mag at float32(1-1e-7) = 1-2^-23 exactly; branchless
// equivalent: den = max(Pp-Pm, 2^-23*Pp)  [R4 bug was 2^-24 here: +0.69
// systematic on every saturated edge -> absmax 3.5. 2^-23 matches ref.]
// Sign via bit-parity XOR (exact == ref's mod-2 arithmetic).
__global__ __launch_bounds__(TPB, 8) void bp_iter(const float* __restrict__ noise_r,
                                                  const float* __restrict__ ew,
                                                  const int* __restrict__ vn_word,
                                                  float* __restrict__ out) {
    __shared__ __align__(16) float lds[LDSW];
    const int b = blockIdx.x;
    const int t = threadIdx.x;

    const float NO   = (float)0.3981071705534972;          // 1/(R*2*10^(EbNo/10))
    const float NSTD = sqrtf((float)(0.3981071705534972 * 0.5));

    // word addresses of this thread's 2 CN rows (chunkA: j=0..3, chunkB: j=4..5)
    const int wA0 = chunk_of(t, 0) * 4,       wB0 = chunk_of(t, 1) * 4;
    const int wA1 = chunk_of(t + TPB, 0) * 4, wB1 = chunk_of(t + TPB, 1) * 4;

    // Hoist the edge->LDS-word map into registers (one-time global read).
    int w[NV / TPB][DV];
#pragma unroll
    for (int k = 0; k < NV / TPB; ++k)
#pragma unroll
        for (int j = 0; j < DV; ++j)
            w[k][j] = vn_word[DV * (t + TPB * k) + j];

    // ---- init: LLRs + first weighted messages (scatter to CN-major slots) ----
    float llr[NV / TPB];
    const float* nb = noise_r + (size_t)b * NV;
#pragma unroll
    for (int k = 0; k < NV / TPB; ++k) {
        int n = t + TPB * k;
        float y = 1.0f + NSTD * nb[n];
        float l = (4.0f * y) / NO;
        llr[k] = l;
#pragma unroll
        for (int j = 0; j < DV; ++j)
            lds[w[k][j]] = l * ew[DV * n + j];
    }
    __syncthreads();

    for (int it = 0; it < NITER; ++it) {
        // ---- CN update: each thread owns 2 check nodes, vector LDS I/O ----
#pragma unroll
        for (int c = 0; c < MC / TPB; ++c) {
            const int wA = c ? wA1 : wA0;
            const int wB = c ? wB1 : wB0;
            float4 f4 = *(const float4*)&lds[wA];
            float2 f2 = *(const float2*)&lds[wB];
            float mw[DC] = {f4.x, f4.y, f4.z, f4.w, f2.x, f2.y};

            float a[DC], bb[DC];
            unsigned int spack = 0u;
#pragma unroll
            for (int j = 0; j < DC; ++j) {
                float u = __expf(-fabsf(mw[j]));
                a[j]  = 1.0f + u;
                bb[j] = 1.0f - u;
                spack |= ((__float_as_uint(mw[j]) >> 31) & 1u) << j;
            }
            unsigned int par = __popc(spack) & 1u;

            // suffix products (right-to-left), then running prefix
            float sp[DC], sm[DC];
            sp[DC - 1] = 1.0f; sm[DC - 1] = 1.0f;
#pragma unroll
            for (int j = DC - 2; j >= 0; --j) {
                sp[j] = sp[j + 1] * a[j + 1];
                sm[j] = sm[j + 1] * bb[j + 1];
            }
            float rp = 1.0f, rm = 1.0f;
            float v[DC];
#pragma unroll
            for (int j = 0; j < DC; ++j) {
                float Pp  = rp * sp[j];
                float Pm  = rm * sm[j];
                float num = Pp + Pm;
                float den = fmaxf(Pp - Pm, 0x1.0p-23f * Pp);   // == ref clip 1-2^-23
                float val = __logf(__fdividef(num, den));      // >= 0 (mod 1-ulp)
                unsigned int sg = ((par ^ (spack >> j)) & 1u) << 31;
                v[j] = __uint_as_float(__float_as_uint(val) | sg);
                rp *= a[j];
                rm *= bb[j];
            }
            *(float4*)&lds[wA] = make_float4(v[0], v[1], v[2], v[3]);
            *(float2*)&lds[wB] = make_float2(v[4], v[5]);
        }
        __syncthreads();

        // ---- VN update: each thread owns 4 variable nodes ----
        if (it < NITER - 1) {
#pragma unroll
            for (int k = 0; k < NV / TPB; ++k) {
                int n = t + TPB * k;
                float c0 = lds[w[k][0]];
                float c1 = lds[w[k][1]];
                float c2 = lds[w[k][2]];
                float tot = llr[k] + (c0 + c1 + c2);
                lds[w[k][0]] = (tot - c0) * ew[DV * n + 0];
                lds[w[k][1]] = (tot - c1) * ew[DV * n + 1];
                lds[w[k][2]] = (tot - c2) * ew[DV * n + 2];
            }
            __syncthreads();
        } else {
#pragma unroll
            for (int k = 0; k < NV / TPB; ++k) {
                int n = t + TPB * k;
                float c0 = lds[w[k][0]];
                float c1 = lds[w[k][1]];
                float c2 = lds[w[k][2]];
                out[(size_t)b * NV + n] = llr[k] + (c0 + c1 + c2);
            }
        }
    }
}

extern "C" void kernel_launch(void* const* d_in, const int* in_sizes, int n_in,
                              void* d_out, int out_size, void* d_ws, size_t ws_size,
                              hipStream_t stream) {
    const float* noise_r = (const float*)d_in[0];
    // d_in[1] = noise_i (unused by reference)
    const float* ew      = (const float*)d_in[2];
    // d_in[3] = vn_idx: known structure e // 3 (edges contiguous per VN)
    const int*   cn_idx  = (const int*)d_in[4];
    float* out = (float*)d_out;

    int* cn_edges = (int*)d_ws;        // NE ints
    int* cn_cnt   = cn_edges + NE;     // MC ints
    int* vn_word  = cn_cnt + MC;       // NE ints

    hipMemsetAsync(cn_cnt, 0, MC * sizeof(int), stream);
    build_cn<<<(NE + 255) / 256, 256, 0, stream>>>(cn_idx, cn_edges, cn_cnt);
    sort_cn<<<(MC + 255) / 256, 256, 0, stream>>>(cn_edges, vn_word);
    bp_iter<<<NB, TPB, 0, stream>>>(noise_r, ew, vn_word, out);
}